// Round 8
// baseline (256.415 us; speedup 1.0000x reference)
//
#include <hip/hip_runtime.h>
#include <hip/hip_bf16.h>

#define B_ 2
#define H_ 16
#define S_ 2048
#define D_ 64
#define BQ 128     // q-rows per block; BOTH teams cover all 128 (split-K, not split-M)
#define BK 64
#define LDSTR 72   // stride 144B; wide LDS ops at the structural 8-cyc floor
#define LOG2E 1.4426950408889634f
#define FIXM 10.0f // fixed softmax shift: p = e^logit * 2^-FIXM, GLOBAL scale ->
                   // partial (acc,l) over disjoint key sets sum with NO rescale

#if __has_builtin(__builtin_amdgcn_exp2f)
#define EXP2F(x) __builtin_amdgcn_exp2f(x)
#else
#define EXP2F(x) __expf((x) * 0.6931471805599453f)
#endif

typedef _Float16 half8 __attribute__((ext_vector_type(8)));
typedef _Float16 half4 __attribute__((ext_vector_type(4)));
typedef __fp16   fp16x2 __attribute__((ext_vector_type(2)));
typedef float floatx4 __attribute__((ext_vector_type(4)));

__global__ __launch_bounds__(512, 4)
void t5_attn_kernel(const float* __restrict__ qg_, const float* __restrict__ kg_,
                    const float* __restrict__ vg_, const float* __restrict__ bt,
                    const int* __restrict__ elen, float* __restrict__ outg_)
{
    // pair-buffer: buf0 = even tile, buf1 = odd tile (consumed concurrently by teams)
    __shared__ __align__(16) _Float16 Kl[2][BK][LDSTR];  // [buf][key][dim]
    __shared__ __align__(16) _Float16 Vt[2][D_][LDSTR];  // [buf][dim][key]
    __shared__ __align__(16) _Float16 Pl[8][32][LDSTR];  // per-wave P; reused as combine buf
    __shared__ float lut[256];                           // bias*log2e - FIXM

    // 1D grid, batch interleaved in bit 0 (R6's FETCH win: L3 absorbs K/V re-reads)
    const int bx   = blockIdx.x;
    const int b    = bx & 1;
    const int h    = (bx >> 1) & 15;
    const int qblk = bx >> 5;
    const int tid  = threadIdx.x;
    const int wave = tid >> 6;
    const int lane = tid & 63;
    const int quad = lane >> 4;
    const int t16  = lane & 15;
    const int team = wave >> 2;   // 0: even key tiles, 1: odd key tiles
    const int wv   = wave & 3;    // row-block within BQ (32 rows each)

    // ---- bias LUT with FIXM folded in
    if (tid < 256) {
        int n = tid;
        int bucket;
        if (n < 16) {
            bucket = n;
        } else {
            int vl = (int)(__log2f((float)n * 0.0625f) * 4.0f);
            bucket = 16 + (vl < 15 ? vl : 15);
        }
        lut[n] = bt[bucket * H_ + h] * LOG2E - FIXM;
    }
    const float sh_next = FIXM - bt[h] * LOG2E;           // all d<=0 (bucket 0)
    const float sh_far  = FIXM - bt[31 * H_ + h] * LOG2E; // all d>=216 (bucket 31)

    // robust event_length read (int32 vs int64 layouts; valid lengths >= 1)
    const int len = (elen[1] == 0) ? elen[2 * b] : elen[b];
    const int ntiles = (len + BK - 1) >> 6;
    const int npairs = (ntiles + 1) >> 1;

    const size_t bh = ((size_t)b * H_ + h) * (size_t)(S_ * D_);
    const float* qg = qg_ + bh;
    const float* kg = kg_ + bh;
    const float* vg = vg_ + bh;
    float*       og = outg_ + bh;

    // ---- Q fragments: 2 row-groups (A-layout build, used in B slot -> S^T = K.Q^T)
    half8 qf[2][2];
    #pragma unroll
    for (int rg = 0; rg < 2; ++rg) {
        const float qscale = 0.125f * LOG2E;
        const int row = qblk * BQ + wv * 32 + rg * 16 + t16;
        const float* qp = qg + (size_t)row * D_ + quad * 8;
        #pragma unroll
        for (int c = 0; c < 2; ++c) {
            const float4* p = reinterpret_cast<const float4*>(qp + c * 32);
            float4 x0 = p[0], x1 = p[1];
            half8 hv;
            hv[0] = (_Float16)(x0.x * qscale); hv[1] = (_Float16)(x0.y * qscale);
            hv[2] = (_Float16)(x0.z * qscale); hv[3] = (_Float16)(x0.w * qscale);
            hv[4] = (_Float16)(x1.x * qscale); hv[5] = (_Float16)(x1.y * qscale);
            hv[6] = (_Float16)(x1.z * qscale); hv[7] = (_Float16)(x1.w * qscale);
            qf[rg][c] = hv;
        }
    }

    floatx4 zero4 = {0.f, 0.f, 0.f, 0.f};
    floatx4 acc[2][4];         // acc[rg][nb][r]: qrow rg*16+quad*4+r, dim nb*16+t16
    float l_[2];               // per-lane partial row-sum for qrow rg*16+t16
    #pragma unroll
    for (int rg = 0; rg < 2; ++rg) {
        #pragma unroll
        for (int nb = 0; nb < 4; ++nb) acc[rg][nb] = zero4;
        l_[rg] = 0.f;
    }

    const int i_lo = qblk * BQ + wv * 32;

    // ---- staging: 512 threads stage a 128-key PAIR (K rows + V transposed)
    const int krow = tid >> 2;            // 0..127 within pair
    const int kc16 = (tid & 3) << 4;      // 16-col chunk
    float4 kx[4];
    float  vxp[16];
    auto prefetch = [&](int pr) {
        const int base = pr * 2 * BK;
        const float4* p = reinterpret_cast<const float4*>(
            kg + ((size_t)(base + krow) * D_ + kc16));
        kx[0] = p[0]; kx[1] = p[1]; kx[2] = p[2]; kx[3] = p[3];
        const int vk = base + (wave << 4);
        #pragma unroll
        for (int j = 0; j < 16; ++j)
            vxp[j] = vg[(size_t)(vk + j) * D_ + lane];
    };
    auto stage = [&]() {
        const int kbuf = krow >> 6, kr = krow & 63;
        #pragma unroll
        for (int half = 0; half < 2; ++half) {
            float4 x0 = kx[half * 2], x1 = kx[half * 2 + 1];
            half8 hv;
            hv[0]=(_Float16)x0.x; hv[1]=(_Float16)x0.y; hv[2]=(_Float16)x0.z; hv[3]=(_Float16)x0.w;
            hv[4]=(_Float16)x1.x; hv[5]=(_Float16)x1.y; hv[6]=(_Float16)x1.z; hv[7]=(_Float16)x1.w;
            *reinterpret_cast<half8*>(&Kl[kbuf][kr][kc16 + half * 8]) = hv;
        }
        const int vbuf = wave >> 2, vk = (wave & 3) << 4;
        #pragma unroll
        for (int half = 0; half < 2; ++half) {
            half8 vv;
            #pragma unroll
            for (int j = 0; j < 8; ++j) vv[j] = (_Float16)vxp[half * 8 + j];
            *reinterpret_cast<half8*>(&Vt[vbuf][lane][vk + half * 8]) = vv;
        }
    };

    prefetch(0);
    stage();
    __syncthreads();

    for (int t = 0; t < npairs; ++t) {
        const int kt = 2 * t + team;          // this team's tile
        const bool mywork = kt < ntiles;      // odd-ntiles tail: team B idles, keeps barriers
        const bool more = (t + 1) < npairs;
        if (more) prefetch(t + 1);            // global->regs, hides under compute

        if (mywork) {
            // ---- S^T = K (Q*log2e/8)^T : row=key (quad*4+r), col=qrow (t16)
            floatx4 sa[2][4];
            #pragma unroll
            for (int rg = 0; rg < 2; ++rg)
                #pragma unroll
                for (int nb = 0; nb < 4; ++nb) sa[rg][nb] = zero4;
            #pragma unroll
            for (int kc = 0; kc < 2; ++kc) {
                #pragma unroll
                for (int nb = 0; nb < 4; ++nb) {
                    half8 af = *reinterpret_cast<const half8*>(
                        &Kl[team][nb * 16 + t16][kc * 32 + quad * 8]);
                    sa[0][nb] = __builtin_amdgcn_mfma_f32_16x16x32_f16(af, qf[0][kc], sa[0][nb], 0, 0, 0);
                    sa[1][nb] = __builtin_amdgcn_mfma_f32_16x16x32_f16(af, qf[1][kc], sa[1][nb], 0, 0, 0);
                }
            }

            // ---- bias + fixed shift (wave-uniform classification over 32 rows)
            const int base = kt * BK;
            if (i_lo + 31 <= base) {             // all d <= 0 -> bucket 0
                #pragma unroll
                for (int rg = 0; rg < 2; ++rg)
                    #pragma unroll
                    for (int nb = 0; nb < 4; ++nb)
                        #pragma unroll
                        for (int r = 0; r < 4; ++r) sa[rg][nb][r] -= sh_next;
            } else if (i_lo >= base + 279) {     // all d >= 216 -> bucket 31
                #pragma unroll
                for (int rg = 0; rg < 2; ++rg)
                    #pragma unroll
                    for (int nb = 0; nb < 4; ++nb)
                        #pragma unroll
                        for (int r = 0; r < 4; ++r) sa[rg][nb][r] -= sh_far;
            } else {
                #pragma unroll
                for (int rg = 0; rg < 2; ++rg) {
                    // d = qrow - key = (i_lo+rg*16+t16) - (base+nb*16+quad*4+r)
                    const int d0 = i_lo + rg * 16 + t16 - base - quad * 4;
                    #pragma unroll
                    for (int nb = 0; nb < 4; ++nb) {
                        #pragma unroll
                        for (int r = 0; r < 4; ++r) {
                            int d = d0 - nb * 16 - r;
                            d = d < 0 ? 0 : (d > 255 ? 255 : d);
                            sa[rg][nb][r] += lut[d];
                        }
                    }
                }
            }
            // key-padding mask on the boundary tile only
            if ((kt == ntiles - 1) && (len & 63)) {
                #pragma unroll
                for (int nb = 0; nb < 4; ++nb) {
                    #pragma unroll
                    for (int r = 0; r < 4; ++r) {
                        bool valid = (base + nb * 16 + quad * 4 + r) < len;
                        #pragma unroll
                        for (int rg = 0; rg < 2; ++rg)
                            sa[rg][nb][r] = valid ? sa[rg][nb][r] : -1e30f;
                    }
                }
            }

            // ---- fixed-shift softmax + partial l
            #pragma unroll
            for (int rg = 0; rg < 2; ++rg) {
                float s = 0.f;
                #pragma unroll
                for (int nb = 0; nb < 4; ++nb)
                    #pragma unroll
                    for (int r = 0; r < 4; ++r) {
                        sa[rg][nb][r] = EXP2F(sa[rg][nb][r]);
                        s += sa[rg][nb][r];
                    }
                l_[rg] += s;
            }

            // ---- P: key-contiguous per lane -> packed b64 writes
            #pragma unroll
            for (int rg = 0; rg < 2; ++rg) {
                #pragma unroll
                for (int nb = 0; nb < 4; ++nb) {
                    fp16x2 lo = __builtin_amdgcn_cvt_pkrtz(sa[rg][nb][0], sa[rg][nb][1]);
                    fp16x2 hi = __builtin_amdgcn_cvt_pkrtz(sa[rg][nb][2], sa[rg][nb][3]);
                    half4 w;
                    w[0] = (_Float16)lo[0]; w[1] = (_Float16)lo[1];
                    w[2] = (_Float16)hi[0]; w[3] = (_Float16)hi[1];
                    *reinterpret_cast<half4*>(
                        &Pl[wave][rg * 16 + t16][nb * 16 + quad * 4]) = w;
                }
            }
            asm volatile("s_waitcnt lgkmcnt(0)" ::: "memory");

            // ---- O += P V
            #pragma unroll
            for (int kc = 0; kc < 2; ++kc) {
                half8 a0 = *reinterpret_cast<const half8*>(
                    &Pl[wave][t16][kc * 32 + quad * 8]);
                half8 a1 = *reinterpret_cast<const half8*>(
                    &Pl[wave][16 + t16][kc * 32 + quad * 8]);
                #pragma unroll
                for (int nb = 0; nb < 4; ++nb) {
                    half8 bv = *reinterpret_cast<const half8*>(
                        &Vt[team][nb * 16 + t16][kc * 32 + quad * 8]);
                    acc[0][nb] = __builtin_amdgcn_mfma_f32_16x16x32_f16(a0, bv, acc[0][nb], 0, 0, 0);
                    acc[1][nb] = __builtin_amdgcn_mfma_f32_16x16x32_f16(a1, bv, acc[1][nb], 0, 0, 0);
                }
            }
        }

        __syncthreads();          // everyone done reading current pair
        if (more) stage();        // overwrite with next pair
        __syncthreads();          // next pair visible
    }

    // ---- split-K combine (common scale: plain sums) + normalize + store
    float* cb = reinterpret_cast<float*>(&Pl[0][0][0]);  // 32KB acc + 512B l
    float lv[2];
    #pragma unroll
    for (int rg = 0; rg < 2; ++rg) {
        lv[rg] = l_[rg];
        lv[rg] += __shfl_xor(lv[rg], 16, 64);
        lv[rg] += __shfl_xor(lv[rg], 32, 64);   // full row sum for qrow rg*16+t16
    }
    if (team == 1) {
        #pragma unroll
        for (int rg = 0; rg < 2; ++rg) {
            #pragma unroll
            for (int nb = 0; nb < 4; ++nb)
                #pragma unroll
                for (int r = 0; r < 4; ++r)
                    cb[wv * 2048 + (rg * 16 + quad * 4 + r) * 64 + nb * 16 + t16]
                        = acc[rg][nb][r];
            if (quad == 0)
                cb[8192 + wv * 32 + rg * 16 + t16] = lv[rg];
        }
    }
    __syncthreads();
    if (team == 0) {
        #pragma unroll
        for (int rg = 0; rg < 2; ++rg) {
            float ltot = lv[rg] + cb[8192 + wv * 32 + rg * 16 + t16];
            float inv = 1.f / ltot;  // for qrow rg*16+t16, replicated across quads
            #pragma unroll
            for (int r = 0; r < 4; ++r) {
                int rowloc = quad * 4 + r;
                float invr = __shfl(inv, (lane & 48) | rowloc, 64);
                const int row = qblk * BQ + wv * 32 + rg * 16 + rowloc;
                #pragma unroll
                for (int nb = 0; nb < 4; ++nb) {
                    float o = acc[rg][nb][r]
                            + cb[wv * 2048 + (rg * 16 + rowloc) * 64 + nb * 16 + t16];
                    og[(size_t)row * D_ + nb * 16 + t16] = o * invr;
                }
            }
        }
    }
}

extern "C" void kernel_launch(void* const* d_in, const int* in_sizes, int n_in,
                              void* d_out, int out_size, void* d_ws, size_t ws_size,
                              hipStream_t stream) {
    const float* q  = (const float*)d_in[0];
    const float* k  = (const float*)d_in[1];
    const float* v  = (const float*)d_in[2];
    const float* bt = (const float*)d_in[3];
    const int*   el = (const int*)d_in[4];
    float* out = (float*)d_out;
    // 512 blocks x 512 threads = 2 blocks/CU x 8 waves -> 16 waves/CU
    t5_attn_kernel<<<dim3((S_ / BQ) * H_ * B_), dim3(512), 0, stream>>>(q, k, v, bt, el, out);
}

// Round 9
// 122.512 us; speedup vs baseline: 2.0930x; 2.0930x over previous
//
#include <hip/hip_runtime.h>
#include <hip/hip_bf16.h>

#define B_ 2
#define H_ 16
#define S_ 2048
#define D_ 64
#define BQ 128     // q-rows per block: 4 waves x 32 rows (2 row-groups of 16)
#define BK 64
#define LDSTR 72   // K/V row stride 144B: 16B-aligned, odd bank-quad spread
#define PSTR 136   // Pl row stride: 128 keys (both tiles) + 8 pad; 272B = 17x16B
#define LOG2E 1.4426950408889634f
#define FIXM 10.0f // fixed softmax shift: p = e^logit * 2^-FIXM (global scale)

#if __has_builtin(__builtin_amdgcn_exp2f)
#define EXP2F(x) __builtin_amdgcn_exp2f(x)
#else
#define EXP2F(x) __expf((x) * 0.6931471805599453f)
#endif

typedef _Float16 half8 __attribute__((ext_vector_type(8)));
typedef _Float16 half4 __attribute__((ext_vector_type(4)));
typedef __fp16   fp16x2 __attribute__((ext_vector_type(2)));
typedef float floatx4 __attribute__((ext_vector_type(4)));

__global__ __launch_bounds__(256, 2)   // 2 waves/SIMD -> 256-VGPR cap: NO spills
void t5_attn_kernel(const float* __restrict__ qg_, const float* __restrict__ kg_,
                    const float* __restrict__ vg_, const float* __restrict__ bt,
                    const int* __restrict__ elen, float* __restrict__ outg_)
{
    // pair buffers: tile 2p -> index 0, tile 2p+1 -> index 1 (both staged together)
    __shared__ __align__(16) _Float16 Kl[2][BK][LDSTR];  // [tile][key][dim]
    __shared__ __align__(16) _Float16 Vt[2][D_][LDSTR];  // [tile][dim][key]
    __shared__ __align__(16) _Float16 Pl[4][32][PSTR];   // per-wave P, both tiles wide
    __shared__ float lut[256];                           // bias*log2e - FIXM

    // 1D grid, batch interleaved in bit 0 (keeps the R6 FETCH/L3 win)
    const int bx   = blockIdx.x;
    const int b    = bx & 1;
    const int h    = (bx >> 1) & 15;
    const int qblk = bx >> 5;
    const int tid  = threadIdx.x;
    const int wave = tid >> 6;
    const int lane = tid & 63;
    const int quad = lane >> 4;
    const int t16  = lane & 15;

    // ---- bias LUT with FIXM folded in
    {
        int n = tid;
        int bucket;
        if (n < 16) {
            bucket = n;
        } else {
            int vl = (int)(__log2f((float)n * 0.0625f) * 4.0f);
            bucket = 16 + (vl < 15 ? vl : 15);
        }
        lut[n] = bt[bucket * H_ + h] * LOG2E - FIXM;
    }
    const float sh_next = FIXM - bt[h] * LOG2E;           // all d<=0 (bucket 0)
    const float sh_far  = FIXM - bt[31 * H_ + h] * LOG2E; // all d>=216 (bucket 31)

    // robust event_length read (int32 vs int64 layouts; valid lengths >= 1)
    const int len = (elen[1] == 0) ? elen[2 * b] : elen[b];
    const int ntiles = (len + BK - 1) >> 6;
    const int npairs = (ntiles + 1) >> 1;

    const size_t bh = ((size_t)b * H_ + h) * (size_t)(S_ * D_);
    const float* qg = qg_ + bh;
    const float* kg = kg_ + bh;
    const float* vg = vg_ + bh;
    float*       og = outg_ + bh;

    // ---- Q fragments: 2 row-groups (A-layout build, used in B slot -> S^T = K.Q^T)
    half8 qf[2][2];
    #pragma unroll
    for (int rg = 0; rg < 2; ++rg) {
        const float qscale = 0.125f * LOG2E;
        const int row = qblk * BQ + wave * 32 + rg * 16 + t16;
        const float* qp = qg + (size_t)row * D_ + quad * 8;
        #pragma unroll
        for (int c = 0; c < 2; ++c) {
            const float4* p = reinterpret_cast<const float4*>(qp + c * 32);
            float4 x0 = p[0], x1 = p[1];
            half8 hv;
            hv[0] = (_Float16)(x0.x * qscale); hv[1] = (_Float16)(x0.y * qscale);
            hv[2] = (_Float16)(x0.z * qscale); hv[3] = (_Float16)(x0.w * qscale);
            hv[4] = (_Float16)(x1.x * qscale); hv[5] = (_Float16)(x1.y * qscale);
            hv[6] = (_Float16)(x1.z * qscale); hv[7] = (_Float16)(x1.w * qscale);
            qf[rg][c] = hv;
        }
    }

    floatx4 zero4 = {0.f, 0.f, 0.f, 0.f};
    floatx4 acc[2][4];         // acc[rg][nb][r]: qrow rg*16+quad*4+r, dim nb*16+t16
    float l_[2];               // per-lane partial row-sum for qrow rg*16+t16
    #pragma unroll
    for (int rg = 0; rg < 2; ++rg) {
        #pragma unroll
        for (int nb = 0; nb < 4; ++nb) acc[rg][nb] = zero4;
        l_[rg] = 0.f;
    }

    const int i_lo = qblk * BQ + wave * 32;

    // ---- staging registers: full 128-key pair, packed to fp16 at load time
    half8 kst[2][2];   // [tile][chunk]: K rows
    half8 vst[2][2];   // [tile][chunk]: V transposed (8 keys for dim=lane)
    const int krow = tid >> 3;            // K: row within tile (2 chunks/thread)
    const int kc8  = (tid & 7) << 3;      // K: 8-col chunk
    auto prefetch = [&](int p) {
        const int pbase = p * 2 * BK;
        #pragma unroll
        for (int t = 0; t < 2; ++t) {
            #pragma unroll
            for (int it = 0; it < 2; ++it) {
                int idx = tid + it * 256;
                int row = idx >> 3, c8 = (idx & 7) << 3;
                const float4* pp = reinterpret_cast<const float4*>(
                    kg + ((size_t)(pbase + t * BK + row) * D_ + c8));
                float4 x0 = pp[0], x1 = pp[1];
                half8 hv;
                hv[0]=(_Float16)x0.x; hv[1]=(_Float16)x0.y; hv[2]=(_Float16)x0.z; hv[3]=(_Float16)x0.w;
                hv[4]=(_Float16)x1.x; hv[5]=(_Float16)x1.y; hv[6]=(_Float16)x1.z; hv[7]=(_Float16)x1.w;
                kst[t][it] = hv;
            }
            #pragma unroll
            for (int it = 0; it < 2; ++it) {
                int key8 = pbase + t * BK + wave * 8 + it * 32;
                half8 vv;
                #pragma unroll
                for (int jj = 0; jj < 8; ++jj)
                    vv[jj] = (_Float16)vg[(size_t)(key8 + jj) * D_ + lane];
                vst[t][it] = vv;
            }
        }
    };
    auto stage = [&]() {
        #pragma unroll
        for (int t = 0; t < 2; ++t) {
            #pragma unroll
            for (int it = 0; it < 2; ++it) {
                int idx = tid + it * 256;
                int row = idx >> 3, c8 = (idx & 7) << 3;
                *reinterpret_cast<half8*>(&Kl[t][row][c8]) = kst[t][it];
                *reinterpret_cast<half8*>(&Vt[t][lane][wave * 8 + it * 32]) = vst[t][it];
            }
        }
    };

    prefetch(0);
    stage();
    __syncthreads();

    for (int p = 0; p < npairs; ++p) {
        const bool more = (p + 1) < npairs;

        // ---- S^T for BOTH tiles: two independent MFMA chains, interleaved
        floatx4 sa[2][2][4];   // [tile][rg][nb]
        #pragma unroll
        for (int t = 0; t < 2; ++t)
            #pragma unroll
            for (int rg = 0; rg < 2; ++rg)
                #pragma unroll
                for (int nb = 0; nb < 4; ++nb) sa[t][rg][nb] = zero4;
        #pragma unroll
        for (int kc = 0; kc < 2; ++kc) {
            #pragma unroll
            for (int nb = 0; nb < 4; ++nb) {
                half8 af0 = *reinterpret_cast<const half8*>(
                    &Kl[0][nb * 16 + t16][kc * 32 + quad * 8]);
                half8 af1 = *reinterpret_cast<const half8*>(
                    &Kl[1][nb * 16 + t16][kc * 32 + quad * 8]);
                sa[0][0][nb] = __builtin_amdgcn_mfma_f32_16x16x32_f16(af0, qf[0][kc], sa[0][0][nb], 0, 0, 0);
                sa[1][0][nb] = __builtin_amdgcn_mfma_f32_16x16x32_f16(af1, qf[0][kc], sa[1][0][nb], 0, 0, 0);
                sa[0][1][nb] = __builtin_amdgcn_mfma_f32_16x16x32_f16(af0, qf[1][kc], sa[0][1][nb], 0, 0, 0);
                sa[1][1][nb] = __builtin_amdgcn_mfma_f32_16x16x32_f16(af1, qf[1][kc], sa[1][1][nb], 0, 0, 0);
            }
        }

        // issue next pair's global loads; they land during softmax/P/PV below
        if (more) prefetch(p + 1);

        // ---- per tile: bias classification + mask + exp + partial l
        #pragma unroll
        for (int t = 0; t < 2; ++t) {
            const int kt = 2 * p + t;
            const int base = kt * BK;
            if (kt >= ntiles) {                  // odd-ntiles tail: mask whole tile
                #pragma unroll
                for (int rg = 0; rg < 2; ++rg)
                    #pragma unroll
                    for (int nb = 0; nb < 4; ++nb)
                        #pragma unroll
                        for (int r = 0; r < 4; ++r) sa[t][rg][nb][r] = -1e30f;
            } else if (i_lo + 31 <= base) {      // all d <= 0 -> bucket 0
                #pragma unroll
                for (int rg = 0; rg < 2; ++rg)
                    #pragma unroll
                    for (int nb = 0; nb < 4; ++nb)
                        #pragma unroll
                        for (int r = 0; r < 4; ++r) sa[t][rg][nb][r] -= sh_next;
            } else if (i_lo >= base + 279) {     // all d >= 216 -> bucket 31
                #pragma unroll
                for (int rg = 0; rg < 2; ++rg)
                    #pragma unroll
                    for (int nb = 0; nb < 4; ++nb)
                        #pragma unroll
                        for (int r = 0; r < 4; ++r) sa[t][rg][nb][r] -= sh_far;
            } else {
                #pragma unroll
                for (int rg = 0; rg < 2; ++rg) {
                    // d = qrow - key = (i_lo+rg*16+t16) - (base+nb*16+quad*4+r)
                    const int d0 = i_lo + rg * 16 + t16 - base - quad * 4;
                    #pragma unroll
                    for (int nb = 0; nb < 4; ++nb) {
                        #pragma unroll
                        for (int r = 0; r < 4; ++r) {
                            int d = d0 - nb * 16 - r;
                            d = d < 0 ? 0 : (d > 255 ? 255 : d);
                            sa[t][rg][nb][r] += lut[d];
                        }
                    }
                }
            }
            if ((kt == ntiles - 1) && (len & 63)) {   // boundary partial mask
                #pragma unroll
                for (int nb = 0; nb < 4; ++nb) {
                    #pragma unroll
                    for (int r = 0; r < 4; ++r) {
                        bool valid = (base + nb * 16 + quad * 4 + r) < len;
                        #pragma unroll
                        for (int rg = 0; rg < 2; ++rg)
                            sa[t][rg][nb][r] = valid ? sa[t][rg][nb][r] : -1e30f;
                    }
                }
            }
            // fixed-shift softmax (64 exps/lane per pair, batched)
            #pragma unroll
            for (int rg = 0; rg < 2; ++rg) {
                float s = 0.f;
                #pragma unroll
                for (int nb = 0; nb < 4; ++nb)
                    #pragma unroll
                    for (int r = 0; r < 4; ++r) {
                        sa[t][rg][nb][r] = EXP2F(sa[t][rg][nb][r]);
                        s += sa[t][rg][nb][r];
                    }
                l_[rg] += s;
            }
        }

        // ---- P writes: both tiles side-by-side in Pl, ONE waitcnt for the pair
        #pragma unroll
        for (int t = 0; t < 2; ++t) {
            #pragma unroll
            for (int rg = 0; rg < 2; ++rg) {
                #pragma unroll
                for (int nb = 0; nb < 4; ++nb) {
                    fp16x2 lo = __builtin_amdgcn_cvt_pkrtz(sa[t][rg][nb][0], sa[t][rg][nb][1]);
                    fp16x2 hi = __builtin_amdgcn_cvt_pkrtz(sa[t][rg][nb][2], sa[t][rg][nb][3]);
                    half4 w;
                    w[0] = (_Float16)lo[0]; w[1] = (_Float16)lo[1];
                    w[2] = (_Float16)hi[0]; w[3] = (_Float16)hi[1];
                    *reinterpret_cast<half4*>(
                        &Pl[wave][rg * 16 + t16][t * 64 + nb * 16 + quad * 4]) = w;
                }
            }
        }
        asm volatile("s_waitcnt lgkmcnt(0)" ::: "memory");  // own wave's writes visible

        // ---- O += P V for both tiles (independent chains)
        #pragma unroll
        for (int t = 0; t < 2; ++t) {
            #pragma unroll
            for (int kc = 0; kc < 2; ++kc) {
                half8 a0 = *reinterpret_cast<const half8*>(
                    &Pl[wave][t16][t * 64 + kc * 32 + quad * 8]);
                half8 a1 = *reinterpret_cast<const half8*>(
                    &Pl[wave][16 + t16][t * 64 + kc * 32 + quad * 8]);
                #pragma unroll
                for (int nb = 0; nb < 4; ++nb) {
                    half8 bv = *reinterpret_cast<const half8*>(
                        &Vt[t][nb * 16 + t16][kc * 32 + quad * 8]);
                    acc[0][nb] = __builtin_amdgcn_mfma_f32_16x16x32_f16(a0, bv, acc[0][nb], 0, 0, 0);
                    acc[1][nb] = __builtin_amdgcn_mfma_f32_16x16x32_f16(a1, bv, acc[1][nb], 0, 0, 0);
                }
            }
        }

        if (more) {
            __syncthreads();      // everyone done reading this pair
            stage();              // regs -> LDS for next pair
            __syncthreads();      // next pair visible
        }
    }

    // ---- epilogue: reduce l across quads, normalize, store
    #pragma unroll
    for (int rg = 0; rg < 2; ++rg) {
        float lv = l_[rg];
        lv += __shfl_xor(lv, 16, 64);
        lv += __shfl_xor(lv, 32, 64);
        float inv = 1.f / lv;  // for qrow rg*16+t16, replicated across quads
        #pragma unroll
        for (int r = 0; r < 4; ++r) {
            int rowloc = quad * 4 + r;
            float invr = __shfl(inv, (lane & 48) | rowloc, 64);  // lane with t16=rowloc
            const int row = qblk * BQ + wave * 32 + rg * 16 + rowloc;
            #pragma unroll
            for (int nb = 0; nb < 4; ++nb)
                og[(size_t)row * D_ + nb * 16 + t16] = acc[rg][nb][r] * invr;
        }
    }
}

extern "C" void kernel_launch(void* const* d_in, const int* in_sizes, int n_in,
                              void* d_out, int out_size, void* d_ws, size_t ws_size,
                              hipStream_t stream) {
    const float* q  = (const float*)d_in[0];
    const float* k  = (const float*)d_in[1];
    const float* v  = (const float*)d_in[2];
    const float* bt = (const float*)d_in[3];
    const int*   el = (const int*)d_in[4];
    float* out = (float*)d_out;
    // 512 blocks x 256 threads; batch interleaved in bit 0 for load balance
    t5_attn_kernel<<<dim3((S_ / BQ) * H_ * B_), dim3(256), 0, stream>>>(q, k, v, bt, el, out);
}